// Round 18
// baseline (1138.106 us; speedup 1.0000x reference)
//
#include <hip/hip_runtime.h>
#include <math.h>

#define PI_D 3.14159265358979323846
#define PI_F 3.14159265358979323846f

// ---------------- workspace layout (float units) ----------------
#define IMG224 50176
static const size_t OFF_FT224F = 0;
static const size_t OFF_FT224I = 2048;
static const size_t OFF_PHW    = 8600;     // 32 floats g1/g0 taps; +32: 648 float2 gpsi
static const size_t OFF_PSI   = 257152;    // 8*50176 (j=0 filters only, R36)
static const size_t OFF_GK    = 1122688;   // 3888 keys
static const size_t OFF_XH    = 1126784;   // 4816896
static const size_t OFF_POOL  = 5943680;
// R32 pools: A0 = A1 = 19267584 floats (192 groups), A23 = 9633792 (real u1, 192 planes).
// R25/R26/R29: spatial-conv identity lineage (sc2pipe back half, s0/E, band-split).
// R33/R34: k_psi FP32 confirmed (941us). R35: packed-real row FFT (917us).
// R36: the ENTIRE 112-level pipeline (C, D, sc2pipe fold2+ifft112) replaced by the
//      exact identity ifft112(fold2(Spec(u)*Psi)) = (u (*) g_psi)(2i,2j) with
//      g_psi = ifft224(psi_j1) truncated at +/-4 (envelope exp(-1.28 x^2): 1e-9 at 4).
//      One banded conv kernel (sc2conv) does conv -> |.| -> g1 blur -> max for all 8 l2
//      per staged band. C/D/sc2pipe/fft112_2d/FT112 tables deleted. Host-exact taps.

// ---------------- helpers ----------------
__device__ inline unsigned fkey(float v) {
    int b = __float_as_int(v);
    return (b >= 0) ? ((unsigned)b | 0x80000000u) : ~(unsigned)b;
}
__device__ inline float funkey(unsigned u) {
    int b = (u & 0x80000000u) ? (int)(u & 0x7fffffffu) : (int)~u;
    return __int_as_float(b);
}
__device__ inline void cmac(float2& a, float2 z, float2 w) {
    a.x += z.x * w.x - z.y * w.y;
    a.y += z.x * w.y + z.y * w.x;
}
__device__ inline float2 cmulc(float2 v, float c, float s) {
    return make_float2(v.x * c - v.y * s, v.x * s + v.y * c);
}

// 16-point DFT, radix-4 x radix-4, constant twiddles. R13-proven.
template<int SGN>
__device__ inline void fft16(float2* x) {
    const float C8  = 0.70710678118654752f;
    const float C16 = 0.92387953251128674f;
    const float S16 = 0.38268343236508977f;
    const float sg = (float)SGN;
    float2 g[16];
#pragma unroll
    for (int b = 0; b < 4; ++b) {
        float2 x0 = x[b], x1 = x[4 + b], x2 = x[8 + b], x3 = x[12 + b];
        float2 e0 = make_float2(x0.x + x2.x, x0.y + x2.y);
        float2 e1 = make_float2(x0.x - x2.x, x0.y - x2.y);
        float2 o0 = make_float2(x1.x + x3.x, x1.y + x3.y);
        float2 o1 = make_float2(x1.x - x3.x, x1.y - x3.y);
        float2 io1 = (SGN > 0) ? make_float2(-o1.y, o1.x) : make_float2(o1.y, -o1.x);
        g[b * 4 + 0] = make_float2(e0.x + o0.x, e0.y + o0.y);
        g[b * 4 + 2] = make_float2(e0.x - o0.x, e0.y - o0.y);
        g[b * 4 + 1] = make_float2(e1.x + io1.x, e1.y + io1.y);
        g[b * 4 + 3] = make_float2(e1.x - io1.x, e1.y - io1.y);
    }
    g[5]  = cmulc(g[5],  C16,  sg * S16);
    g[6]  = cmulc(g[6],  C8,   sg * C8);
    g[7]  = cmulc(g[7],  S16,  sg * C16);
    g[9]  = cmulc(g[9],  C8,   sg * C8);
    g[10] = (SGN > 0) ? make_float2(-g[10].y, g[10].x)
                      : make_float2(g[10].y, -g[10].x);
    g[11] = cmulc(g[11], -C8,  sg * C8);
    g[13] = cmulc(g[13], S16,  sg * C16);
    g[14] = cmulc(g[14], -C8,  sg * C8);
    g[15] = cmulc(g[15], -C16, -sg * S16);
#pragma unroll
    for (int p = 0; p < 4; ++p) {
        float2 x0 = g[p], x1 = g[4 + p], x2 = g[8 + p], x3 = g[12 + p];
        float2 e0 = make_float2(x0.x + x2.x, x0.y + x2.y);
        float2 e1 = make_float2(x0.x - x2.x, x0.y - x2.y);
        float2 o0 = make_float2(x1.x + x3.x, x1.y + x3.y);
        float2 o1 = make_float2(x1.x - x3.x, x1.y - x3.y);
        float2 io1 = (SGN > 0) ? make_float2(-o1.y, o1.x) : make_float2(o1.y, -o1.x);
        x[p + 0]  = make_float2(e0.x + o0.x, e0.y + o0.y);
        x[p + 8]  = make_float2(e0.x - o0.x, e0.y - o0.y);
        x[p + 4]  = make_float2(e1.x + io1.x, e1.y + io1.y);
        x[p + 12] = make_float2(e1.x - io1.x, e1.y - io1.y);
    }
}

// ---------------- table builders ----------------
__global__ void k_fact(float2* o, int N1, int N2, double sign, double scale, int r2) {
    int base3 = N1 * N1 + N2 * N2 + N2 * N1;
    int total = base3 + (r2 ? 63 : 0);
    int N = N1 * N2;
    for (int i = blockIdx.x * blockDim.x + threadIdx.x; i < total; i += blockDim.x * gridDim.x) {
        double ang; double sc = 1.0;
        if (i < N1 * N1) {
            int n1 = i / N1, k1 = i % N1;
            ang = sign * 2.0 * PI_D * (double)((n1 * k1) % N1) / (double)N1;
        } else if (i < N1 * N1 + N2 * N2) {
            int j = i - N1 * N1; int n2 = j / N2, k2 = j % N2;
            ang = sign * 2.0 * PI_D * (double)((n2 * k2) % N2) / (double)N2;
            sc = scale;
        } else if (i < base3) {
            int j = i - N1 * N1 - N2 * N2; int n2 = j / N1, k1 = j % N1;
            ang = sign * 2.0 * PI_D * (double)((n2 * k1) % N) / (double)N;
        } else if (i < base3 + 49) {
            int j = i - base3; int n = j / 7, k = j % 7;
            ang = sign * 2.0 * PI_D * (double)((n * k) % 7) / 7.0;
            sc = scale;
        } else {
            int k = i - base3 - 49;
            ang = sign * 2.0 * PI_D * (double)k / 14.0;
        }
        o[i] = make_float2((float)(sc * cos(ang)), (float)(sc * sin(ang)));
    }
}

// R33/R36: FP32 transcendentals; builds ONLY j=0 filters (j=1 handled by host taps).
__global__ void k_psi(float* out) {
    int i = blockIdx.x * blockDim.x + threadIdx.x;
    if (i >= 8 * IMG224) return;
    int l = i / IMG224, p = i % IMG224;
    int r = p / 224, c = p % 224;
    float fr = (r < 112) ? (float)r : (float)(r - 224);
    float fc = (c < 112) ? (float)c : (float)(c - 224);
    float wx = 2.0f * PI_F * fr / 224.0f;
    float wy = 2.0f * PI_F * fc / 224.0f;
    float theta = (float)l * PI_F / 8.0f;
    float xi = 3.0f * PI_F / 4.0f;
    float sg = 0.8f;
    float ct = cosf(theta), st = sinf(theta);
    float u = ct * wx + st * wy;
    float v = -st * wx + ct * wy;
    float vs = v * 2.0f;
    float s2 = 0.5f * sg * sg;
    float gab = expf(-s2 * ((u - xi) * (u - xi) + vs * vs));
    float gau = expf(-s2 * (u * u + vs * vs));
    float kap = expf(-s2 * xi * xi);
    out[i] = gab - kap * gau;
}

__global__ void k_zero(unsigned* gk, int n) {
    int i = blockIdx.x * blockDim.x + threadIdx.x;
    if (i < n) gk[i] = 0u;
}

// ---------------- rk: row pass, two-stage, fused in LDS (R8..R35-proven) ----
// RMODE: 0 = complex filter-multiply, 1 = real, 2 = packed-real (R35).
template<int N1, int N2, int TA, int FOLD, int BS, int RMODE, int SGN>
__global__ __launch_bounds__(BS) void rk(
    const void* __restrict__ inBase, int inShift,
    const float* __restrict__ fltBase, int fltMask,
    const float2* __restrict__ FT, float2* __restrict__ out,
    int swzImg, int inStride, int inOff)
{
    constexpr int N = N1 * N2;
    constexpr int NIN = N * FOLD;
    constexpr int ZS = N + 2;
    constexpr int TS = N2 * (N1 + 1);
    constexpr int K1H = N1 / 2;
    constexpr int TAC = (RMODE == 2) ? TA / 2 : TA;
    __shared__ float2 Z[TA * ZS];
    __shared__ float2 T[TA * TS];
    const float2* TW = FT + N1 * N1 + N2 * N2;
    const int bx = blockIdx.x, a0 = blockIdx.y * TA, t = threadIdx.x;
    int gIn, gFlt, gOut;
    if (swzImg > 0) {
        int img = bx % swzImg, sub = bx / swzImg;
        gIn = img * inStride + inOff + (sub >> 3);
        gFlt = sub & fltMask;
        gOut = img * (gridDim.x / swzImg) + sub;
    } else if (swzImg < 0) {
        int lgF = -swzImg;
        int xcd = bx & 7, loc = bx >> 3;
        int img = xcd * ((int)gridDim.x >> (3 + lgF)) + (loc >> lgF);
        int f = loc & ((1 << lgF) - 1);
        gIn = img; gFlt = f & fltMask; gOut = (img << lgF) + f;
    } else {
        gIn = bx >> inShift; gFlt = bx & fltMask; gOut = bx;
    }

    if (RMODE == 1) {
        const float* in = (const float*)inBase + (size_t)gIn * N * N;
#pragma unroll
        for (int r = 0; r < TA; ++r)
            for (int b = t; b < N; b += BS)
                Z[r * ZS + b] = make_float2(in[(size_t)(a0 + r) * N + b], 0.f);
    } else if (RMODE == 2) {
        const float* in = (const float*)inBase + (size_t)gIn * N * N;
#pragma unroll
        for (int pr = 0; pr < TAC; ++pr)
            for (int b = t; b < N; b += BS) {
                size_t base = (size_t)(a0 + 2 * pr) * N + b;
                Z[pr * ZS + b] = make_float2(in[base], in[base + N]);
            }
    } else {
        const float2* in = (const float2*)inBase + (size_t)gIn * (NIN * NIN);
        const float* flt = fltBase + (size_t)gFlt * (NIN * NIN);
        const float s = 1.0f / (float)(FOLD * FOLD);
#pragma unroll
        for (int r = 0; r < TA; ++r) {
            int a = a0 + r;
            for (int b = t; b < N; b += BS) {
                float re = 0.f, im = 0.f;
#pragma unroll
                for (int i = 0; i < FOLD; ++i)
#pragma unroll
                    for (int j = 0; j < FOLD; ++j) {
                        int idx = (a + N * i) * NIN + (b + N * j);
                        float2 v = in[idx];
                        float f = flt[idx];
                        re += v.x * f; im += v.y * f;
                    }
                Z[r * ZS + b] = make_float2(re * s, im * s);
            }
        }
    }
    __syncthreads();
    for (int idx = t; idx < TAC * N2 * 2; idx += BS) {
        int r = idx / (N2 * 2);
        int rem = idx % (N2 * 2);
        int n2 = rem / 2, h = rem % 2;
        float2 xx[N1];
#pragma unroll
        for (int n1 = 0; n1 < N1; ++n1) xx[n1] = Z[r * ZS + n1 * N2 + n2];
        fft16<SGN>(xx);
#pragma unroll
        for (int kk = 0; kk < K1H; ++kk) {
            int k1 = h * K1H + kk;
            float2 tw = TW[n2 * N1 + k1];
            T[r * TS + n2 * (N1 + 1) + k1] = cmulc(xx[k1], tw.x, tw.y);
        }
    }
    __syncthreads();
    {
        const float2* W7  = FT + N1 * N1 + N2 * N2 + N2 * N1;
        const float2* T14 = W7 + 49;
        for (int idx = t; idx < TAC * N1; idx += BS) {
            int r = idx / N1, k1 = idx % N1;
            float2 E[7], O[7];
#pragma unroll
            for (int k = 0; k < 7; ++k) { E[k] = make_float2(0.f, 0.f); O[k] = make_float2(0.f, 0.f); }
            for (int m = 0; m < 7; ++m) {
                float2 te = T[r * TS + (2 * m) * (N1 + 1) + k1];
                float2 to = T[r * TS + (2 * m + 1) * (N1 + 1) + k1];
#pragma unroll
                for (int k = 0; k < 7; ++k) {
                    float2 w = W7[m * 7 + k];
                    cmac(E[k], te, w);
                    cmac(O[k], to, w);
                }
            }
#pragma unroll
            for (int k = 0; k < 14; ++k) {
                float2 tw = T14[k];
                float2 o_ = O[k % 7];
                float2 X = E[k % 7];
                X.x += o_.x * tw.x - o_.y * tw.y;
                X.y += o_.x * tw.y + o_.y * tw.x;
                Z[r * ZS + k1 + N1 * k] = X;
            }
        }
    }
    __syncthreads();
    if (RMODE == 2) {
#pragma unroll
        for (int pr = 0; pr < TAC; ++pr) {
            float2* oe = out + ((size_t)gOut * N + (a0 + 2 * pr)) * N;
            float2* oo = oe + N;
            for (int b = t; b < N; b += BS) {
                int mb = (b == 0) ? 0 : N - b;
                float2 zk = Z[pr * ZS + b];
                float2 zm = Z[pr * ZS + mb];
                oe[b] = make_float2(0.5f * (zk.x + zm.x), 0.5f * (zk.y - zm.y));
                oo[b] = make_float2(0.5f * (zk.y + zm.y), 0.5f * (zm.x - zk.x));
            }
        }
    } else {
#pragma unroll
        for (int r = 0; r < TA; ++r) {
            float2* o = out + ((size_t)gOut * N + (a0 + r)) * N;
            for (int b = t; b < N; b += BS) o[b] = Z[r * ZS + b];
        }
    }
}

// ---------------- ck1: col pass stage 1 — fft16 columns (R13-proven) ----------------
template<int N1, int N2, int SPLIT, int BS, int SGN>
__global__ __launch_bounds__(BS) void ck1(
    const float2* __restrict__ in, const float2* __restrict__ FT, float2* __restrict__ out)
{
    constexpr int N = N1 * N2;
    constexpr int NC = N / SPLIT;
    const float2* TW = FT + N1 * N1 + N2 * N2;
    const int g = blockIdx.x / SPLIT, half = blockIdx.x % SPLIT;
    const int n2 = blockIdx.y, t = threadIdx.x;
    if (2 * t >= NC) return;
    const int b0 = 2 * t + half * NC;
    const float2* I = in + (size_t)g * N * N;
    float2 a0[16], a1[16];
#pragma unroll
    for (int n1 = 0; n1 < 16; ++n1) {
        float4 v = *reinterpret_cast<const float4*>(&I[(size_t)(n1 * N2 + n2) * N + b0]);
        a0[n1] = make_float2(v.x, v.y);
        a1[n1] = make_float2(v.z, v.w);
    }
    fft16<SGN>(a0);
    fft16<SGN>(a1);
#pragma unroll
    for (int k1 = 0; k1 < 16; ++k1) {
        float2 tw = TW[n2 * N1 + k1];
        float2 r0 = cmulc(a0[k1], tw.x, tw.y);
        float2 r1 = cmulc(a1[k1], tw.x, tw.y);
        *reinterpret_cast<float4*>(&out[((size_t)g * N + (k1 * N2 + n2)) * N + b0]) =
            make_float4(r0.x, r0.y, r1.x, r1.y);
    }
}

// ---------------- ck2: col pass stage 2 + MODE (R25-proven streaming E/O DIT) --------
template<int N1, int N2, int SPLIT, int MODE, int BS>
__global__ __launch_bounds__(BS) void ck2(
    const float2* __restrict__ in, const float2* __restrict__ FT,
    float2* __restrict__ outc, float* __restrict__ outr)
{
    constexpr int N = N1 * N2;
    constexpr int NC = N / SPLIT;
    const int g = blockIdx.x / SPLIT, half = blockIdx.x % SPLIT;
    const int k1 = blockIdx.y, t = threadIdx.x;
    if (2 * t >= NC) return;
    const int b0 = 2 * t + half * NC;
    const float2* I = in + (size_t)g * N * N;
    const float2* W7  = FT + N1 * N1 + N2 * N2 + N2 * N1;
    const float2* T14 = W7 + 49;
    float2 E0[7], E1[7], O0[7], O1[7];
#pragma unroll
    for (int k = 0; k < 7; ++k) {
        E0[k] = make_float2(0.f, 0.f); E1[k] = make_float2(0.f, 0.f);
        O0[k] = make_float2(0.f, 0.f); O1[k] = make_float2(0.f, 0.f);
    }
#pragma unroll
    for (int m = 0; m < 7; ++m) {
        float4 ve = *reinterpret_cast<const float4*>(&I[(size_t)(k1 * 14 + 2 * m) * N + b0]);
        float4 vo = *reinterpret_cast<const float4*>(&I[(size_t)(k1 * 14 + 2 * m + 1) * N + b0]);
        float2 ve0 = make_float2(ve.x, ve.y), ve1 = make_float2(ve.z, ve.w);
        float2 vo0 = make_float2(vo.x, vo.y), vo1 = make_float2(vo.z, vo.w);
#pragma unroll
        for (int k = 0; k < 7; ++k) {
            float2 w = W7[m * 7 + k];
            cmac(E0[k], ve0, w); cmac(E1[k], ve1, w);
            cmac(O0[k], vo0, w); cmac(O1[k], vo1, w);
        }
    }
#pragma unroll
    for (int k = 0; k < 14; ++k) {
        float2 tw = T14[k];
        float2 r0 = E0[k % 7], r1 = E1[k % 7];
        float2 o0 = O0[k % 7], o1 = O1[k % 7];
        r0.x += o0.x * tw.x - o0.y * tw.y;
        r0.y += o0.x * tw.y + o0.y * tw.x;
        r1.x += o1.x * tw.x - o1.y * tw.y;
        r1.y += o1.x * tw.y + o1.y * tw.x;
        if (MODE == 0) {
            *reinterpret_cast<float4*>(&outc[((size_t)g * N + (k1 + N1 * k)) * N + b0]) =
                make_float4(r0.x, r0.y, r1.x, r1.y);
        } else {
            size_t o = ((size_t)g * N + (k1 + N1 * k)) * N + b0;
            outr[o]     = sqrtf(r0.x * r0.x + r0.y * r0.y);
            outr[o + 1] = sqrtf(r1.x * r1.x + r1.y * r1.y);
        }
    }
}

// ---------------- sc2conv (R36): u -> (u (*) g_psi)(2i,2j) -> |.| -> g1 blur -> max --
// Exact identity: ifft112(fold2(Spec(u)*Psi_j1)) = (u (*) ifft224(Psi_j1))(2i,2j).
// Per block: (plane p, band of BA=8 S-rows). Stage u band (57 rows, +/-4 col halo) in
// LDS; for each of 8 l2: 9x9 complex conv at stride 2 -> V (25x112 real |.|) -> row
// blur (g1, mod112) -> col blur + max -> atomicMax. All wraps handled at staging/cols.
template<int BA, int BS>
__global__ __launch_bounds__(BS) void sc2conv(
    const float* __restrict__ uBase, const float2* __restrict__ gpsiG,
    const float* __restrict__ taps, unsigned* __restrict__ gk,
    int slotBase, int ps)
{
    constexpr int NB = 56 / BA;          // 7 bands
    constexpr int UR = 4 * BA + 25;      // 57 staged u rows
    constexpr int UW = 232;              // 224 + 4 left halo + 4 right halo
    constexpr int VR = 2 * BA + 9;       // 25 V rows
    __shared__ float U[UR * UW];
    __shared__ float V[VR * 112];
    __shared__ float B1[VR * 56];
    __shared__ float2 GT[8 * 81];
    __shared__ float red[BS / 64];
    const int t = threadIdx.x, bx = blockIdx.x;
    const int p = bx / NB, band = bx % NB;
    const int a0 = band * BA;
    const int img = p >> ps, sub = p & ((1 << ps) - 1);
    const float* u = uBase + (size_t)p * 50176;
    float gw[6];
#pragma unroll
    for (int i = 0; i < 6; ++i) gw[i] = taps[i];
    for (int i = t; i < 8 * 81; i += BS) GT[i] = gpsiG[i];
    // stage u rows (r0 + rr) mod 224, cols with +/-4 halo: U[rr][cc] = u[gr][(cc-4) mod 224]
    const int r0 = 4 * a0 - 14;
    for (int idx = t; idx < UR * UW; idx += BS) {
        int rr = idx / UW, cc = idx % UW;
        int gr = r0 + rr;
        gr += (gr < 0) ? 224 : 0;
        gr -= (gr >= 224) ? 224 : 0;
        int gc = cc - 4;
        gc += (gc < 0) ? 224 : 0;
        gc -= (gc >= 224) ? 224 : 0;
        U[idx] = u[gr * 224 + gc];
    }
    __syncthreads();

    for (int l2 = 0; l2 < 8; ++l2) {
        const float2* G = GT + l2 * 81;
        // conv + modulus -> V. V global row i = (2a0-5+ri) mod 112; u local row for tap m:
        // 2*ri + 4 - m (in [2ri, 2ri+8]); u local col for tap n: 2j + (4-n) (in [2j, 2j+8]).
        for (int idx = t; idx < VR * 112; idx += BS) {
            int ri = idx / 112, j = idx % 112;
            float re = 0.f, im = 0.f;
#pragma unroll
            for (int m = -4; m <= 4; ++m) {
                const float* urow = U + (2 * ri + 4 - m) * UW + 2 * j;
#pragma unroll
                for (int n = -4; n <= 4; ++n) {
                    float2 g = G[(m + 4) * 9 + (n + 4)];
                    float uv = urow[4 - n];
                    re += uv * g.x; im += uv * g.y;
                }
            }
            V[idx] = sqrtf(re * re + im * im);
        }
        __syncthreads();
        // row blur: B1[ri][b] = sum_n g1|n| * V[ri][(2b+n) mod 112]
        for (int idx = t; idx < VR * 56; idx += BS) {
            int ri = idx / 56, b = idx % 56;
            int c0 = 2 * b;
            const float* vr = V + ri * 112;
            float acc = gw[0] * vr[c0];
#pragma unroll
            for (int m = 1; m <= 5; ++m) {
                int cm = c0 - m; cm += (cm < 0) ? 112 : 0;
                int cq = c0 + m; cq -= (cq >= 112) ? 112 : 0;
                acc += gw[m] * (vr[cm] + vr[cq]);
            }
            B1[idx] = acc;
        }
        __syncthreads();
        // col blur + max: S(a,b), a = a0+la; B1 local row of (2a+m) = 2la + 5 + m.
        float mx = -INFINITY;
        for (int idx = t; idx < BA * 56; idx += BS) {
            int la = idx / 56, b = idx % 56;
            int base = 2 * la + 5;
            float acc = gw[0] * B1[base * 56 + b];
#pragma unroll
            for (int m = 1; m <= 5; ++m)
                acc += gw[m] * (B1[(base - m) * 56 + b] + B1[(base + m) * 56 + b]);
            mx = fmaxf(mx, acc);
        }
        for (int off = 32; off > 0; off >>= 1) mx = fmaxf(mx, __shfl_down(mx, off, 64));
        if ((t & 63) == 0) red[t >> 6] = mx;
        __syncthreads();
        if (t == 0) {
#pragma unroll
            for (int w = 1; w < BS / 64; ++w) mx = fmaxf(mx, red[w]);
            atomicMax(&gk[img * 81 + slotBase + (sub << 3) + l2], fkey(mx));
        }
        __syncthreads();
    }
}

// ---------------- s1conv (R29): banded s0/s1 separable conv with g0 ------------------
template<int SB, int BS>
__global__ __launch_bounds__(BS) void s1conv(
    const float* __restrict__ inBase, const float* __restrict__ taps,
    unsigned* __restrict__ gk, int slotBase, int slotShift, int slotMask)
{
    constexpr int OPB = 56 / SB;
    constexpr int IR  = 4 * OPB + 19;
    __shared__ float R2[IR][56];
    __shared__ float red[BS / 64];
    const int g = blockIdx.x, t = threadIdx.x;
    const int band = g % SB, grp = g / SB;
    const float* u = inBase + (size_t)grp * 50176;
    float gw[12];
#pragma unroll
    for (int i = 0; i < 12; ++i) gw[i] = taps[i];
    const int rbase = 4 * OPB * band - 11;
    for (int idx = t; idx < IR * 56; idx += BS) {
        int j = idx % 56, rr = idx / 56;
        int riw = rbase + rr;
        riw += (riw < 0) ? 224 : 0;
        riw -= (riw >= 224) ? 224 : 0;
        const float* row = u + riw * 224;
        int c0 = 4 * j;
        float acc = gw[0] * row[c0];
#pragma unroll
        for (int m = 1; m <= 11; ++m) {
            int cm = c0 - m; cm += (cm < 0) ? 224 : 0;
            int cq = c0 + m; cq -= (cq >= 224) ? 224 : 0;
            acc += gw[m] * (row[cm] + row[cq]);
        }
        R2[rr][j] = acc;
    }
    __syncthreads();
    float mx = -INFINITY;
    for (int idx = t; idx < OPB * 56; idx += BS) {
        int j = idx % 56, l = idx / 56;
        int base = 4 * l + 11;
        float acc = gw[0] * R2[base][j];
#pragma unroll
        for (int m = 1; m <= 11; ++m)
            acc += gw[m] * (R2[base - m][j] + R2[base + m][j]);
        mx = fmaxf(mx, acc);
    }
    for (int off = 32; off > 0; off >>= 1) mx = fmaxf(mx, __shfl_down(mx, off, 64));
    if ((t & 63) == 0) red[t >> 6] = mx;
    __syncthreads();
    if (t == 0) {
#pragma unroll
        for (int w = 1; w < BS / 64; ++w) mx = fmaxf(mx, red[w]);
        int slot = slotBase + ((grp >> slotShift) * 81) + (grp & slotMask);
        atomicMax(&gk[slot], fkey(mx));
    }
}

// ---------------- classifier head ----------------
__global__ void k_linear(const unsigned* __restrict__ gk, const float* __restrict__ Wl,
                         const float* __restrict__ bl, float* __restrict__ out)
{
    int i = blockIdx.x * blockDim.x + threadIdx.x;
    if (i >= 16 * 1000) return;
    int b = i / 1000, o = i % 1000;
    float s = bl[o];
    for (int f = 0; f < 243; ++f)
        s += funkey(gk[b * 243 + f]) * Wl[o * 243 + f];
    out[i] = s;
}

// ---------------- host-side tables (R27/R36): g1/g0 taps + gpsi 9x9 kernels ----------
static float g_all[32 + 8 * 81 * 2];
static bool g_tab_init = false;
static void host_tables() {
    if (g_tab_init) return;
    const double s2p = 0.5 * 1.6 * 1.6;
    // g1 (112-grid blur taps)
    for (int m = 0; m < 16; ++m) {
        double acc = 0.0;
        for (int k = 0; k < 112; ++k) {
            double w0 = 2.0 * PI_D * (double)k / 224.0;
            double w1 = 2.0 * PI_D * (double)(k - 112) / 224.0;
            double F = 0.5 * (exp(-s2p * w0 * w0) + exp(-s2p * w1 * w1));
            acc += F * cos(2.0 * PI_D * (double)k * (double)m / 112.0);
        }
        g_all[m] = (float)(acc / 112.0);
    }
    // g0 (224-grid blur taps)
    for (int m = 0; m < 16; ++m) {
        double acc = 0.0;
        for (int k = 0; k < 224; ++k) {
            double fr = (k < 112) ? (double)k : (double)(k - 224);
            double w = 2.0 * PI_D * fr / 224.0;
            acc += exp(-s2p * w * w) * cos(2.0 * PI_D * (double)k * (double)m / 224.0);
        }
        g_all[16 + m] = (float)(acc / 224.0);
    }
    // gpsi[l][m+4][n+4] = ifft224(psi_{j=1,l})(m,n), exact truncated 9x9
    static double innRe[224][9], innIm[224][9];
    const double xi = (3.0 * PI_D / 4.0) / 2.0, sg = 1.6;
    const double s2 = 0.5 * sg * sg;
    const double kap = exp(-s2 * xi * xi);
    for (int l = 0; l < 8; ++l) {
        double th = (double)l * PI_D / 8.0;
        double ct = cos(th), st = sin(th);
        for (int kr = 0; kr < 224; ++kr)
            for (int n = 0; n < 9; ++n) { innRe[kr][n] = 0.0; innIm[kr][n] = 0.0; }
        for (int kr = 0; kr < 224; ++kr) {
            double fr = (kr < 112) ? (double)kr : (double)(kr - 224);
            double wx = 2.0 * PI_D * fr / 224.0;
            for (int kc = 0; kc < 224; ++kc) {
                double fc = (kc < 112) ? (double)kc : (double)(kc - 224);
                double wy = 2.0 * PI_D * fc / 224.0;
                double uu = ct * wx + st * wy;
                double vv = -st * wx + ct * wy;
                double vs = vv / 0.5;
                double val = exp(-s2 * ((uu - xi) * (uu - xi) + vs * vs))
                           - kap * exp(-s2 * (uu * uu + vs * vs));
                for (int n = 0; n < 9; ++n) {
                    double ang = 2.0 * PI_D * fc * (double)(n - 4) / 224.0;
                    innRe[kr][n] += val * cos(ang);
                    innIm[kr][n] += val * sin(ang);
                }
            }
        }
        for (int m = 0; m < 9; ++m)
            for (int n = 0; n < 9; ++n) {
                double re = 0.0, im = 0.0;
                for (int kr = 0; kr < 224; ++kr) {
                    double fr = (kr < 112) ? (double)kr : (double)(kr - 224);
                    double ang = 2.0 * PI_D * fr * (double)(m - 4) / 224.0;
                    double c = cos(ang), s = sin(ang);
                    re += innRe[kr][n] * c - innIm[kr][n] * s;
                    im += innRe[kr][n] * s + innIm[kr][n] * c;
                }
                g_all[32 + 2 * (l * 81 + m * 9 + n)]     = (float)(re / 50176.0);
                g_all[32 + 2 * (l * 81 + m * 9 + n) + 1] = (float)(im / 50176.0);
            }
    }
    g_tab_init = true;
}

// ---------------- launch ----------------
extern "C" void kernel_launch(void* const* d_in, const int* in_sizes, int n_in,
                              void* d_out, int out_size, void* d_ws, size_t ws_size,
                              hipStream_t stream)
{
    const float* x  = (const float*)d_in[0];
    const float* Wl = (const float*)d_in[1];
    const float* bl = (const float*)d_in[2];
    float* out = (float*)d_out;
    float* ws = (float*)d_ws;

    float2* FT224F = (float2*)(ws + OFF_FT224F);
    float2* FT224I = (float2*)(ws + OFF_FT224I);
    float* TAPS = ws + OFF_PHW;                    // [0..15] g1, [16..31] g0
    float2* GPSI = (float2*)(ws + OFF_PHW + 32);   // 648 float2
    float* PSI0 = ws + OFF_PSI;
    unsigned* GK = (unsigned*)(ws + OFF_GK);
    float2* XH  = (float2*)(ws + OFF_XH);
    float* A0  = ws + OFF_POOL;            // 19267584 floats
    float* A1  = A0 + 19267584;            // 19267584 floats
    float* A23 = A1 + 19267584;            // 9633792 floats (real u1, 192 planes)

    // tables
    host_tables();
    hipMemcpyAsync(TAPS, g_all, sizeof(g_all), hipMemcpyHostToDevice, stream);
    k_fact<<<4, 256, 0, stream>>>(FT224F, 16, 14, -1.0, 1.0, 1);
    k_fact<<<4, 256, 0, stream>>>(FT224I, 16, 14,  1.0, 1.0 / 224.0, 1);
    k_psi<<<(8 * IMG224 + 255) / 256, 256, 0, stream>>>(PSI0);
    k_zero<<<(3888 + 255) / 256, 256, 0, stream>>>(GK, 3888);

    // ---- fft2(x) -> XH (packed-real rows, R35) ----
    rk<16, 14, 4, 1, 128, 2, -1><<<dim3(48, 56), 128, 0, stream>>>(x, 0, nullptr, 0, FT224F, (float2*)A0, 0, 0, 0);
    ck1<16, 14, 2, 64, -1><<<dim3(96, 14), 64, 0, stream>>>((float2*)A0, FT224F, (float2*)A1);
    ck2<16, 14, 2, 0, 64><<<dim3(96, 16), 64, 0, stream>>>((float2*)A1, FT224F, XH, nullptr);

    // ---- s0 = (x (*) g0)(4i,4j) -> slot img*81+0 ----
    s1conv<8, 256><<<48 * 8, 256, 0, stream>>>(x, TAPS + 16, GK, 0, 0, 0);

    // ---- first order j1=1 (R36): direct conv on x; slots img*81 + 9 + l2 ----
    sc2conv<8, 256><<<48 * 7, 256, 0, stream>>>(x, GPSI, TAPS, GK, 9, 0);

    // ---- 2x-batched first order j1=0 (+ conv second order); l1 = 4*c2 + f ----
    for (int c2 = 0; c2 < 2; ++c2) {
        // A: ifft rows of xh*psi0[l1] -> A0 (192 groups; 4-per-img XCD mapping)
        rk<16, 14, 4, 1, 128, 0, 1><<<dim3(192, 56), 128, 0, stream>>>(
            XH, 1, PSI0 + (size_t)(4 * c2) * IMG224, 3, FT224I, (float2*)A0, -2, 0, 0);
        // B: ifft cols + |.| -> A23 (real u1, 192 planes; plane = img*4 + f)
        ck1<16, 14, 2, 64, 1><<<dim3(384, 14), 64, 0, stream>>>((float2*)A0, FT224I, (float2*)A1);
        ck2<16, 14, 2, 1, 64><<<dim3(384, 16), 64, 0, stream>>>((float2*)A1, FT224I, nullptr, A23);
        // E: s1 = (u1 (*) g0)(4i,4j) -> slot img*81 + 1 + 4*c2 + f
        s1conv<8, 256><<<192 * 8, 256, 0, stream>>>(A23, TAPS + 16, GK, 1 + 4 * c2, 2, 3);
        // second order (R36): conv on u1; slots img*81 + 17 + 32c2 + 8f + l2
        sc2conv<8, 256><<<192 * 7, 256, 0, stream>>>(A23, GPSI, TAPS, GK, 17 + 32 * c2, 2);
    }

    // head
    k_linear<<<(16000 + 255) / 256, 256, 0, stream>>>(GK, Wl, bl, out);
}

// Round 19
// 916.860 us; speedup vs baseline: 1.2413x; 1.2413x over previous
//
#include <hip/hip_runtime.h>
#include <math.h>

#define PI_D 3.14159265358979323846
#define PI_F 3.14159265358979323846f

// ---------------- workspace layout (float units) ----------------
#define IMG224 50176
#define IMG112 12544
// factorized DFT tables per (N,dir): [W1:N1*N1 | W2:N2*N2 | TW:N2*N1 | (r2: W7:49 | T14:14)]
static const size_t OFF_FT224F = 0;
static const size_t OFF_FT224I = 2048;
static const size_t OFF_FT112F = 4096;
static const size_t OFF_FT112I = 6144;
static const size_t OFF_PHW    = 8600;     // 32 floats: taps g1 (112-grid) | taps g0 (224-grid)
static const size_t OFF_PSI   = 257152;    // 16*50176
static const size_t OFF_GK    = 1122688;   // 3888 keys
static const size_t OFF_XH    = 1126784;   // 4816896
static const size_t OFF_POOL  = 5943680;
// R32 pools: A0 = A1 = 19267584 floats (192 groups), A23 = 9633792 (real u1, 192 planes).
// Ladder: R19 sc2pipe fusion (1533) -> R22 sym-DFT7 (1180) -> R25 conv-identity back half
// (1068) -> R29 banded s1conv (963) -> R32 c-batching (961) -> R33/34 k_psi FP32 (941)
// -> R35 packed-real row FFT (917 BEST).
// R36: psi-as-9x9-conv: REGRESSED both axes — (a) LDS-operand-bound (346us/dispatch,
//      10.9M bank conflicts; dense conv needs 81 LDS reads/point); (b) absmax 0.00049->
//      0.00171: psi slant-axis spatial sigma=1.25px => 9x9 truncation error ~6e-3, NOT
//      1e-9. Conv-identity works for smooth monotone phi only. REVERTED to R35.

// ---------------- helpers ----------------
__device__ inline unsigned fkey(float v) {
    int b = __float_as_int(v);
    return (b >= 0) ? ((unsigned)b | 0x80000000u) : ~(unsigned)b;
}
__device__ inline float funkey(unsigned u) {
    int b = (u & 0x80000000u) ? (int)(u & 0x7fffffffu) : (int)~u;
    return __int_as_float(b);
}
__device__ inline void cmac(float2& a, float2 z, float2 w) {
    a.x += z.x * w.x - z.y * w.y;
    a.y += z.x * w.y + z.y * w.x;
}
__device__ inline float2 cmulc(float2 v, float c, float s) {
    return make_float2(v.x * c - v.y * s, v.x * s + v.y * c);
}

// Symmetric DFT-7 coefficients (R22-proven): W[7-m][k] = conj(W[m][k]).
struct C7 { float s; float wr[3][3]; float wi[3][3]; };
__device__ inline void ld7(const float2* __restrict__ W7, C7& c) {
    c.s = W7[0].x;
#pragma unroll
    for (int m = 1; m <= 3; ++m)
#pragma unroll
        for (int k = 1; k <= 3; ++k) {
            float2 w = W7[m * 7 + k];
            c.wr[m - 1][k - 1] = w.x;
            c.wi[m - 1][k - 1] = w.y;
        }
}
__device__ inline void dft7(const C7& c, const float2 t[7], float2 X[7]) {
    float2 a1 = make_float2(t[1].x + t[6].x, t[1].y + t[6].y);
    float2 b1 = make_float2(t[1].x - t[6].x, t[1].y - t[6].y);
    float2 a2 = make_float2(t[2].x + t[5].x, t[2].y + t[5].y);
    float2 b2 = make_float2(t[2].x - t[5].x, t[2].y - t[5].y);
    float2 a3 = make_float2(t[3].x + t[4].x, t[3].y + t[4].y);
    float2 b3 = make_float2(t[3].x - t[4].x, t[3].y - t[4].y);
    float bx = c.s * t[0].x, by = c.s * t[0].y;
    X[0] = make_float2(c.s * (t[0].x + a1.x + a2.x + a3.x),
                       c.s * (t[0].y + a1.y + a2.y + a3.y));
#pragma unroll
    for (int k = 0; k < 3; ++k) {
        float Px = c.wr[0][k] * a1.x + c.wr[1][k] * a2.x + c.wr[2][k] * a3.x;
        float Py = c.wr[0][k] * a1.y + c.wr[1][k] * a2.y + c.wr[2][k] * a3.y;
        float Qx = c.wi[0][k] * b1.x + c.wi[1][k] * b2.x + c.wi[2][k] * b3.x;
        float Qy = c.wi[0][k] * b1.y + c.wi[1][k] * b2.y + c.wi[2][k] * b3.y;
        X[k + 1] = make_float2(bx + Px - Qy, by + Py + Qx);
        X[6 - k] = make_float2(bx + Px + Qy, by + Py - Qx);
    }
}

// 16-point DFT, radix-4 x radix-4, constant twiddles. R13-proven.
template<int SGN>
__device__ inline void fft16(float2* x) {
    const float C8  = 0.70710678118654752f;
    const float C16 = 0.92387953251128674f;
    const float S16 = 0.38268343236508977f;
    const float sg = (float)SGN;
    float2 g[16];
#pragma unroll
    for (int b = 0; b < 4; ++b) {
        float2 x0 = x[b], x1 = x[4 + b], x2 = x[8 + b], x3 = x[12 + b];
        float2 e0 = make_float2(x0.x + x2.x, x0.y + x2.y);
        float2 e1 = make_float2(x0.x - x2.x, x0.y - x2.y);
        float2 o0 = make_float2(x1.x + x3.x, x1.y + x3.y);
        float2 o1 = make_float2(x1.x - x3.x, x1.y - x3.y);
        float2 io1 = (SGN > 0) ? make_float2(-o1.y, o1.x) : make_float2(o1.y, -o1.x);
        g[b * 4 + 0] = make_float2(e0.x + o0.x, e0.y + o0.y);
        g[b * 4 + 2] = make_float2(e0.x - o0.x, e0.y - o0.y);
        g[b * 4 + 1] = make_float2(e1.x + io1.x, e1.y + io1.y);
        g[b * 4 + 3] = make_float2(e1.x - io1.x, e1.y - io1.y);
    }
    g[5]  = cmulc(g[5],  C16,  sg * S16);
    g[6]  = cmulc(g[6],  C8,   sg * C8);
    g[7]  = cmulc(g[7],  S16,  sg * C16);
    g[9]  = cmulc(g[9],  C8,   sg * C8);
    g[10] = (SGN > 0) ? make_float2(-g[10].y, g[10].x)
                      : make_float2(g[10].y, -g[10].x);
    g[11] = cmulc(g[11], -C8,  sg * C8);
    g[13] = cmulc(g[13], S16,  sg * C16);
    g[14] = cmulc(g[14], -C8,  sg * C8);
    g[15] = cmulc(g[15], -C16, -sg * S16);
#pragma unroll
    for (int p = 0; p < 4; ++p) {
        float2 x0 = g[p], x1 = g[4 + p], x2 = g[8 + p], x3 = g[12 + p];
        float2 e0 = make_float2(x0.x + x2.x, x0.y + x2.y);
        float2 e1 = make_float2(x0.x - x2.x, x0.y - x2.y);
        float2 o0 = make_float2(x1.x + x3.x, x1.y + x3.y);
        float2 o1 = make_float2(x1.x - x3.x, x1.y - x3.y);
        float2 io1 = (SGN > 0) ? make_float2(-o1.y, o1.x) : make_float2(o1.y, -o1.x);
        x[p + 0]  = make_float2(e0.x + o0.x, e0.y + o0.y);
        x[p + 8]  = make_float2(e0.x - o0.x, e0.y - o0.y);
        x[p + 4]  = make_float2(e1.x + io1.x, e1.y + io1.y);
        x[p + 12] = make_float2(e1.x - io1.x, e1.y - io1.y);
    }
}

// ---------------- table builders ----------------
__global__ void k_fact(float2* o, int N1, int N2, double sign, double scale, int r2) {
    int base3 = N1 * N1 + N2 * N2 + N2 * N1;
    int total = base3 + (r2 ? 63 : 0);
    int N = N1 * N2;
    for (int i = blockIdx.x * blockDim.x + threadIdx.x; i < total; i += blockDim.x * gridDim.x) {
        double ang; double sc = 1.0;
        if (i < N1 * N1) {
            int n1 = i / N1, k1 = i % N1;
            ang = sign * 2.0 * PI_D * (double)((n1 * k1) % N1) / (double)N1;
        } else if (i < N1 * N1 + N2 * N2) {
            int j = i - N1 * N1; int n2 = j / N2, k2 = j % N2;
            ang = sign * 2.0 * PI_D * (double)((n2 * k2) % N2) / (double)N2;
            sc = scale;
        } else if (i < base3) {
            int j = i - N1 * N1 - N2 * N2; int n2 = j / N1, k1 = j % N1;
            ang = sign * 2.0 * PI_D * (double)((n2 * k1) % N) / (double)N;
        } else if (i < base3 + 49) {
            int j = i - base3; int n = j / 7, k = j % 7;
            ang = sign * 2.0 * PI_D * (double)((n * k) % 7) / 7.0;
            sc = scale;
        } else {
            int k = i - base3 - 49;
            ang = sign * 2.0 * PI_D * (double)k / 14.0;
        }
        o[i] = make_float2((float)(sc * cos(ang)), (float)(sc * sin(ang)));
    }
}

// R33: FP32 transcendentals (hw-rate); confirmed R34 via clock-reference re-measure.
__global__ void k_psi(float* out) {
    int i = blockIdx.x * blockDim.x + threadIdx.x;
    if (i >= 16 * IMG224) return;
    int jl = i / IMG224, p = i % IMG224;
    int r = p / 224, c = p % 224;
    int j = jl >> 3, l = jl & 7;
    float fr = (r < 112) ? (float)r : (float)(r - 224);
    float fc = (c < 112) ? (float)c : (float)(c - 224);
    float wx = 2.0f * PI_F * fr / 224.0f;
    float wy = 2.0f * PI_F * fc / 224.0f;
    float theta = (float)l * PI_F / 8.0f;
    float xi = (3.0f * PI_F / 4.0f) / (float)(1 << j);
    float sg = 0.8f * (float)(1 << j);
    float ct = cosf(theta), st = sinf(theta);
    float u = ct * wx + st * wy;
    float v = -st * wx + ct * wy;
    float vs = v * 2.0f;
    float s2 = 0.5f * sg * sg;
    float gab = expf(-s2 * ((u - xi) * (u - xi) + vs * vs));
    float gau = expf(-s2 * (u * u + vs * vs));
    float kap = expf(-s2 * xi * xi);
    out[i] = gab - kap * gau;
}

__global__ void k_zero(unsigned* gk, int n) {
    int i = blockIdx.x * blockDim.x + threadIdx.x;
    if (i < n) gk[i] = 0u;
}

// ---------------- rk: row pass, two-stage (N=N1*N2), fused in LDS (R8..R18-proven) ----
// RMODE: 0 = complex-fold (filter multiply), 1 = real input,
//        2 = packed-real (R35): rows (2r,2r+1) packed as z=a+ib, TA/2 FFTs, LDS-local
//        Hermitian unpack A(k)=(Z(k)+conj(Z(-k)))/2, B(k)=(Z(k)-conj(Z(-k)))/(2i).
// swzImg < 0 (R23/R32): XCD-grouped mapping with lgF = -swzImg filters per image.
template<int N1, int N2, int TA, int FOLD, int BS, int RMODE, int SGN>
__global__ __launch_bounds__(BS) void rk(
    const void* __restrict__ inBase, int inShift,
    const float* __restrict__ fltBase, int fltMask,
    const float2* __restrict__ FT, float2* __restrict__ out,
    int swzImg, int inStride, int inOff)
{
    constexpr int N = N1 * N2;
    constexpr int NIN = N * FOLD;
    constexpr int ZS = N + 2;
    constexpr int TS = N2 * (N1 + 1);
    constexpr int K1H = N1 / 2;
    constexpr int TAC = (RMODE == 2) ? TA / 2 : TA;   // compute-row count
    __shared__ float2 Z[TA * ZS];
    __shared__ float2 T[TA * TS];
    const float2* TW = FT + N1 * N1 + N2 * N2;
    const int bx = blockIdx.x, a0 = blockIdx.y * TA, t = threadIdx.x;
    int gIn, gFlt, gOut;
    if (swzImg > 0) {
        int img = bx % swzImg, sub = bx / swzImg;
        gIn = img * inStride + inOff + (sub >> 3);
        gFlt = sub & fltMask;
        gOut = img * (gridDim.x / swzImg) + sub;
    } else if (swzImg < 0) {
        int lgF = -swzImg;
        int xcd = bx & 7, loc = bx >> 3;
        int img = xcd * ((int)gridDim.x >> (3 + lgF)) + (loc >> lgF);
        int f = loc & ((1 << lgF) - 1);
        gIn = img; gFlt = f & fltMask; gOut = (img << lgF) + f;
    } else {
        gIn = bx >> inShift; gFlt = bx & fltMask; gOut = bx;
    }

    if (RMODE == 1) {
        const float* in = (const float*)inBase + (size_t)gIn * N * N;
#pragma unroll
        for (int r = 0; r < TA; ++r)
            for (int b = t; b < N; b += BS)
                Z[r * ZS + b] = make_float2(in[(size_t)(a0 + r) * N + b], 0.f);
    } else if (RMODE == 2) {
        const float* in = (const float*)inBase + (size_t)gIn * N * N;
#pragma unroll
        for (int pr = 0; pr < TAC; ++pr)
            for (int b = t; b < N; b += BS) {
                size_t base = (size_t)(a0 + 2 * pr) * N + b;
                Z[pr * ZS + b] = make_float2(in[base], in[base + N]);
            }
    } else {
        const float2* in = (const float2*)inBase + (size_t)gIn * (NIN * NIN);
        const float* flt = fltBase + (size_t)gFlt * (NIN * NIN);
        const float s = 1.0f / (float)(FOLD * FOLD);
#pragma unroll
        for (int r = 0; r < TA; ++r) {
            int a = a0 + r;
            for (int b = t; b < N; b += BS) {
                float re = 0.f, im = 0.f;
#pragma unroll
                for (int i = 0; i < FOLD; ++i)
#pragma unroll
                    for (int j = 0; j < FOLD; ++j) {
                        int idx = (a + N * i) * NIN + (b + N * j);
                        float2 v = in[idx];
                        float f = flt[idx];
                        re += v.x * f; im += v.y * f;
                    }
                Z[r * ZS + b] = make_float2(re * s, im * s);
            }
        }
    }
    __syncthreads();
    for (int idx = t; idx < TAC * N2 * 2; idx += BS) {
        int r = idx / (N2 * 2);
        int rem = idx % (N2 * 2);
        int n2 = rem / 2, h = rem % 2;
        float2 xx[N1];
#pragma unroll
        for (int n1 = 0; n1 < N1; ++n1) xx[n1] = Z[r * ZS + n1 * N2 + n2];
        fft16<SGN>(xx);
#pragma unroll
        for (int kk = 0; kk < K1H; ++kk) {
            int k1 = h * K1H + kk;
            float2 tw = TW[n2 * N1 + k1];
            T[r * TS + n2 * (N1 + 1) + k1] = cmulc(xx[k1], tw.x, tw.y);
        }
    }
    __syncthreads();
    {
        const float2* W7  = FT + N1 * N1 + N2 * N2 + N2 * N1;
        const float2* T14 = W7 + 49;
        for (int idx = t; idx < TAC * N1; idx += BS) {
            int r = idx / N1, k1 = idx % N1;
            float2 E[7], O[7];
#pragma unroll
            for (int k = 0; k < 7; ++k) { E[k] = make_float2(0.f, 0.f); O[k] = make_float2(0.f, 0.f); }
            for (int m = 0; m < 7; ++m) {
                float2 te = T[r * TS + (2 * m) * (N1 + 1) + k1];
                float2 to = T[r * TS + (2 * m + 1) * (N1 + 1) + k1];
#pragma unroll
                for (int k = 0; k < 7; ++k) {
                    float2 w = W7[m * 7 + k];
                    cmac(E[k], te, w);
                    cmac(O[k], to, w);
                }
            }
#pragma unroll
            for (int k = 0; k < 14; ++k) {
                float2 tw = T14[k];
                float2 o_ = O[k % 7];
                float2 X = E[k % 7];
                X.x += o_.x * tw.x - o_.y * tw.y;
                X.y += o_.x * tw.y + o_.y * tw.x;
                Z[r * ZS + k1 + N1 * k] = X;
            }
        }
    }
    __syncthreads();
    if (RMODE == 2) {
        // LDS-local Hermitian unpack: rows 2pr, 2pr+1 from packed spectrum pr.
#pragma unroll
        for (int pr = 0; pr < TAC; ++pr) {
            float2* oe = out + ((size_t)gOut * N + (a0 + 2 * pr)) * N;
            float2* oo = oe + N;
            for (int b = t; b < N; b += BS) {
                int mb = (b == 0) ? 0 : N - b;
                float2 zk = Z[pr * ZS + b];
                float2 zm = Z[pr * ZS + mb];
                oe[b] = make_float2(0.5f * (zk.x + zm.x), 0.5f * (zk.y - zm.y));
                oo[b] = make_float2(0.5f * (zk.y + zm.y), 0.5f * (zm.x - zk.x));
            }
        }
    } else {
#pragma unroll
        for (int r = 0; r < TA; ++r) {
            float2* o = out + ((size_t)gOut * N + (a0 + r)) * N;
            for (int b = t; b < N; b += BS) o[b] = Z[r * ZS + b];
        }
    }
}

// ---------------- ck1: col pass stage 1 — fft16 columns (R13-proven) ----------------
template<int N1, int N2, int SPLIT, int BS, int SGN>
__global__ __launch_bounds__(BS) void ck1(
    const float2* __restrict__ in, const float2* __restrict__ FT, float2* __restrict__ out)
{
    constexpr int N = N1 * N2;
    constexpr int NC = N / SPLIT;
    const float2* TW = FT + N1 * N1 + N2 * N2;
    const int g = blockIdx.x / SPLIT, half = blockIdx.x % SPLIT;
    const int n2 = blockIdx.y, t = threadIdx.x;
    if (2 * t >= NC) return;
    const int b0 = 2 * t + half * NC;
    const float2* I = in + (size_t)g * N * N;
    float2 a0[16], a1[16];
#pragma unroll
    for (int n1 = 0; n1 < 16; ++n1) {
        float4 v = *reinterpret_cast<const float4*>(&I[(size_t)(n1 * N2 + n2) * N + b0]);
        a0[n1] = make_float2(v.x, v.y);
        a1[n1] = make_float2(v.z, v.w);
    }
    fft16<SGN>(a0);
    fft16<SGN>(a1);
#pragma unroll
    for (int k1 = 0; k1 < 16; ++k1) {
        float2 tw = TW[n2 * N1 + k1];
        float2 r0 = cmulc(a0[k1], tw.x, tw.y);
        float2 r1 = cmulc(a1[k1], tw.x, tw.y);
        *reinterpret_cast<float4*>(&out[((size_t)g * N + (k1 * N2 + n2)) * N + b0]) =
            make_float4(r0.x, r0.y, r1.x, r1.y);
    }
}

// ---------------- ck2: col pass stage 2 + MODE (R25-proven streaming E/O DIT) --------
template<int N1, int N2, int SPLIT, int MODE, int BS>
__global__ __launch_bounds__(BS) void ck2(
    const float2* __restrict__ in, const float2* __restrict__ FT,
    float2* __restrict__ outc, float* __restrict__ outr)
{
    constexpr int N = N1 * N2;
    constexpr int NC = N / SPLIT;
    const int g = blockIdx.x / SPLIT, half = blockIdx.x % SPLIT;
    const int k1 = blockIdx.y, t = threadIdx.x;
    if (2 * t >= NC) return;
    const int b0 = 2 * t + half * NC;
    const float2* I = in + (size_t)g * N * N;
    const float2* W7  = FT + N1 * N1 + N2 * N2 + N2 * N1;
    const float2* T14 = W7 + 49;
    float2 E0[7], E1[7], O0[7], O1[7];
#pragma unroll
    for (int k = 0; k < 7; ++k) {
        E0[k] = make_float2(0.f, 0.f); E1[k] = make_float2(0.f, 0.f);
        O0[k] = make_float2(0.f, 0.f); O1[k] = make_float2(0.f, 0.f);
    }
#pragma unroll
    for (int m = 0; m < 7; ++m) {
        float4 ve = *reinterpret_cast<const float4*>(&I[(size_t)(k1 * 14 + 2 * m) * N + b0]);
        float4 vo = *reinterpret_cast<const float4*>(&I[(size_t)(k1 * 14 + 2 * m + 1) * N + b0]);
        float2 ve0 = make_float2(ve.x, ve.y), ve1 = make_float2(ve.z, ve.w);
        float2 vo0 = make_float2(vo.x, vo.y), vo1 = make_float2(vo.z, vo.w);
#pragma unroll
        for (int k = 0; k < 7; ++k) {
            float2 w = W7[m * 7 + k];
            cmac(E0[k], ve0, w); cmac(E1[k], ve1, w);
            cmac(O0[k], vo0, w); cmac(O1[k], vo1, w);
        }
    }
#pragma unroll
    for (int k = 0; k < 14; ++k) {
        float2 tw = T14[k];
        float2 r0 = E0[k % 7], r1 = E1[k % 7];
        float2 o0 = O0[k % 7], o1 = O1[k % 7];
        r0.x += o0.x * tw.x - o0.y * tw.y;
        r0.y += o0.x * tw.y + o0.y * tw.x;
        r1.x += o1.x * tw.x - o1.y * tw.y;
        r1.y += o1.x * tw.y + o1.y * tw.x;
        if (MODE == 0) {
            *reinterpret_cast<float4*>(&outc[((size_t)g * N + (k1 + N1 * k)) * N + b0]) =
                make_float4(r0.x, r0.y, r1.x, r1.y);
        } else {
            size_t o = ((size_t)g * N + (k1 + N1 * k)) * N + b0;
            outr[o]     = sqrtf(r0.x * r0.x + r0.y * r0.y);
            outr[o + 1] = sqrtf(r1.x * r1.x + r1.y * r1.y);
        }
    }
}

// ---------------- fft112_2d: full in-LDS 2D 112-pt FFT (16x7 Cooley-Tukey) -------------
// R22: symmetric DFT-7 stage2. R23: rows-stage1 remap; EPI=1 fuses |.| into final write.
template<int SGN, int BS, int EPI>
__device__ inline void fft112_2d(float2* Z, const float2* __restrict__ FT, int t)
{
    constexpr int ZS = 113;
    constexpr int NCH = (112 * 16 + BS - 1) / BS;
    const float2* W2 = FT + 256;        // 7x7 (carries 1/112 for inverse)
    const float2* TW = FT + 256 + 49;   // TW[n2*16+k1]
    C7 c7; ld7(W2, c7);
    // ---- rows stage1 ----
    for (int idx = t; idx < 112 * 7; idx += BS) {
        int r = idx % 112, n2 = idx / 112;
        float2 xx[16];
#pragma unroll
        for (int n1 = 0; n1 < 16; ++n1) xx[n1] = Z[r * ZS + n1 * 7 + n2];
        fft16<SGN>(xx);
#pragma unroll
        for (int k1 = 0; k1 < 16; ++k1) {
            float2 tw = TW[n2 * 16 + k1];
            Z[r * ZS + k1 * 7 + n2] = cmulc(xx[k1], tw.x, tw.y);
        }
    }
    __syncthreads();
    // ---- rows stage2: symmetric DFT-7 ----
    {
        float2 tv[NCH][7];
#pragma unroll
        for (int c = 0; c < NCH; ++c) {
            int idx = c * BS + t;
            if (idx < 112 * 16) {
                int r = idx >> 4, k1 = idx & 15;
#pragma unroll
                for (int m = 0; m < 7; ++m) tv[c][m] = Z[r * ZS + k1 * 7 + m];
            }
        }
        __syncthreads();
#pragma unroll
        for (int c = 0; c < NCH; ++c) {
            int idx = c * BS + t;
            if (idx < 112 * 16) {
                int r = idx >> 4, k1 = idx & 15;
                float2 X[7];
                dft7(c7, tv[c], X);
#pragma unroll
                for (int k = 0; k < 7; ++k) Z[r * ZS + k1 + 16 * k] = X[k];
            }
        }
    }
    __syncthreads();
    // ---- cols stage1 ----
    for (int idx = t; idx < 112 * 7; idx += BS) {
        int b = idx % 112, n2 = idx / 112;
        float2 xx[16];
#pragma unroll
        for (int n1 = 0; n1 < 16; ++n1) xx[n1] = Z[(n1 * 7 + n2) * ZS + b];
        fft16<SGN>(xx);
#pragma unroll
        for (int k1 = 0; k1 < 16; ++k1) {
            float2 tw = TW[n2 * 16 + k1];
            Z[(k1 * 7 + n2) * ZS + b] = cmulc(xx[k1], tw.x, tw.y);
        }
    }
    __syncthreads();
    // ---- cols stage2: symmetric DFT-7; EPI=1 writes (|X|, 0) ----
    {
        float2 tv[NCH][7];
#pragma unroll
        for (int c = 0; c < NCH; ++c) {
            int idx = c * BS + t;
            if (idx < 112 * 16) {
                int b = idx >> 4, k1 = idx & 15;
#pragma unroll
                for (int m = 0; m < 7; ++m) tv[c][m] = Z[(k1 * 7 + m) * ZS + b];
            }
        }
        __syncthreads();
#pragma unroll
        for (int c = 0; c < NCH; ++c) {
            int idx = c * BS + t;
            if (idx < 112 * 16) {
                int b = idx >> 4, k1 = idx & 15;
                float2 X[7];
                dft7(c7, tv[c], X);
#pragma unroll
                for (int k = 0; k < 7; ++k) {
                    Z[(k1 + 16 * k) * ZS + b] =
                        EPI ? make_float2(sqrtf(X[k].x * X[k].x + X[k].y * X[k].y), 0.f)
                            : X[k];
                }
            }
        }
    }
    __syncthreads();
}

// ---------------- sc2pipe: the entire 112-level chain in ONE kernel -------------------
// Per block: fold2(in*psi) -> ifft2(112)+|.| -> R25: separable 11-tap circular conv of
// real u2 with g1 = ifft112(phi1), sampled at (2i,2j) -> max -> atomicMax.
template<int BS>
__global__ __launch_bounds__(BS) void sc2pipe(
    const float2* __restrict__ inBase, const float* __restrict__ psiBase,
    const float* __restrict__ taps, const float2* __restrict__ FTI,
    unsigned* __restrict__ gk, int slotBase, int inStride, int subShift)
{
    constexpr int ZS = 113;
    __shared__ float2 Z[112 * ZS];
    __shared__ float2 F[56 * 57];      // reused as 112x57 float scratch for row blur
    __shared__ float red[BS / 64];
    const int t = threadIdx.x, bx = blockIdx.x;
    const int nimg = (int)gridDim.x >> subShift;
    const int xcd = bx & 7, local = bx >> 3;
    const int img = xcd * (nimg >> 3) + (local >> subShift);
    const int sub = local & ((1 << subShift) - 1);
    const float2* in = inBase + (size_t)(img * inStride + (sub >> 3)) * (224 * 224);
    const float* flt = psiBase + (size_t)(sub & 7) * (224 * 224);
    float gw[6];
#pragma unroll
    for (int i = 0; i < 6; ++i) gw[i] = taps[i];

    // ---- stage: fold2(in * psi) -> Z ----
    for (int idx = t; idx < 112 * 112; idx += BS) {
        int a = idx / 112, b = idx % 112;
        float re = 0.f, im = 0.f;
#pragma unroll
        for (int i = 0; i < 2; ++i)
#pragma unroll
            for (int j = 0; j < 2; ++j) {
                int p = (a + 112 * i) * 224 + (b + 112 * j);
                float2 v = in[p]; float f = flt[p];
                re += v.x * f; im += v.y * f;
            }
        Z[a * ZS + b] = make_float2(re * 0.25f, im * 0.25f);
    }
    __syncthreads();

    fft112_2d<1, BS, 1>(Z, FTI, t);       // inverse fft2 + fused |.| -> Z.x = u2 (real)

    // ---- R25 row blur ----
    float* Ft = (float*)F;
    for (int idx = t; idx < 112 * 56; idx += BS) {
        int r = idx % 112, cp = idx / 112;
        int c0 = 2 * cp;
        float acc = gw[0] * Z[r * ZS + c0].x;
#pragma unroll
        for (int m = 1; m <= 5; ++m) {
            int cm = c0 - m; cm += (cm < 0) ? 112 : 0;
            int cq = c0 + m; cq -= (cq >= 112) ? 112 : 0;
            acc += gw[m] * (Z[r * ZS + cm].x + Z[r * ZS + cq].x);
        }
        Ft[r * 57 + cp] = acc;
    }
    __syncthreads();

    // ---- R25 col blur + max ----
    float mx = -INFINITY;
    for (int idx = t; idx < 56 * 56; idx += BS) {
        int j = idx % 56, ip = idx / 56;
        int r0 = 2 * ip;
        float acc = gw[0] * Ft[r0 * 57 + j];
#pragma unroll
        for (int m = 1; m <= 5; ++m) {
            int ra = r0 - m; ra += (ra < 0) ? 112 : 0;
            int rb = r0 + m; rb -= (rb >= 112) ? 112 : 0;
            acc += gw[m] * (Ft[ra * 57 + j] + Ft[rb * 57 + j]);
        }
        mx = fmaxf(mx, acc);
    }
    for (int off = 32; off > 0; off >>= 1) mx = fmaxf(mx, __shfl_down(mx, off, 64));
    if ((t & 63) == 0) red[t >> 6] = mx;
    __syncthreads();
    if (t == 0) {
#pragma unroll
        for (int w = 1; w < BS / 64; ++w) mx = fmaxf(mx, red[w]);
        atomicMax(&gk[img * 81 + slotBase + sub], fkey(mx));
    }
}

// ---------------- s1conv (R29): banded s0/s1 separable conv with g0 ------------------
template<int SB, int BS>
__global__ __launch_bounds__(BS) void s1conv(
    const float* __restrict__ inBase, const float* __restrict__ taps,
    unsigned* __restrict__ gk, int slotBase, int slotShift, int slotMask)
{
    constexpr int OPB = 56 / SB;
    constexpr int IR  = 4 * OPB + 19;
    __shared__ float R2[IR][56];
    __shared__ float red[BS / 64];
    const int g = blockIdx.x, t = threadIdx.x;
    const int band = g % SB, grp = g / SB;
    const float* u = inBase + (size_t)grp * 50176;
    float gw[12];
#pragma unroll
    for (int i = 0; i < 12; ++i) gw[i] = taps[i];
    const int rbase = 4 * OPB * band - 11;
    for (int idx = t; idx < IR * 56; idx += BS) {
        int j = idx % 56, rr = idx / 56;
        int riw = rbase + rr;
        riw += (riw < 0) ? 224 : 0;
        riw -= (riw >= 224) ? 224 : 0;
        const float* row = u + riw * 224;
        int c0 = 4 * j;
        float acc = gw[0] * row[c0];
#pragma unroll
        for (int m = 1; m <= 11; ++m) {
            int cm = c0 - m; cm += (cm < 0) ? 224 : 0;
            int cq = c0 + m; cq -= (cq >= 224) ? 224 : 0;
            acc += gw[m] * (row[cm] + row[cq]);
        }
        R2[rr][j] = acc;
    }
    __syncthreads();
    float mx = -INFINITY;
    for (int idx = t; idx < OPB * 56; idx += BS) {
        int j = idx % 56, l = idx / 56;
        int base = 4 * l + 11;
        float acc = gw[0] * R2[base][j];
#pragma unroll
        for (int m = 1; m <= 11; ++m)
            acc += gw[m] * (R2[base - m][j] + R2[base + m][j]);
        mx = fmaxf(mx, acc);
    }
    for (int off = 32; off > 0; off >>= 1) mx = fmaxf(mx, __shfl_down(mx, off, 64));
    if ((t & 63) == 0) red[t >> 6] = mx;
    __syncthreads();
    if (t == 0) {
#pragma unroll
        for (int w = 1; w < BS / 64; ++w) mx = fmaxf(mx, red[w]);
        int slot = slotBase + ((grp >> slotShift) * 81) + (grp & slotMask);
        atomicMax(&gk[slot], fkey(mx));
    }
}

// ---------------- classifier head ----------------
__global__ void k_linear(const unsigned* __restrict__ gk, const float* __restrict__ Wl,
                         const float* __restrict__ bl, float* __restrict__ out)
{
    int i = blockIdx.x * blockDim.x + threadIdx.x;
    if (i >= 16 * 1000) return;
    int b = i / 1000, o = i % 1000;
    float s = bl[o];
    for (int f = 0; f < 243; ++f)
        s += funkey(gk[b * 243 + f]) * Wl[o * 243 + f];
    out[i] = s;
}

// ---------------- host-side tap computation (R27) ----------------
static float g_taps[32];
static bool g_taps_init = false;
static void host_taps() {
    if (g_taps_init) return;
    const double s2 = 0.5 * 1.6 * 1.6;
    for (int m = 0; m < 16; ++m) {
        double acc = 0.0;
        for (int k = 0; k < 112; ++k) {
            double w0 = 2.0 * PI_D * (double)k / 224.0;
            double w1 = 2.0 * PI_D * (double)(k - 112) / 224.0;
            double F = 0.5 * (exp(-s2 * w0 * w0) + exp(-s2 * w1 * w1));
            acc += F * cos(2.0 * PI_D * (double)k * (double)m / 112.0);
        }
        g_taps[m] = (float)(acc / 112.0);
    }
    for (int m = 0; m < 16; ++m) {
        double acc = 0.0;
        for (int k = 0; k < 224; ++k) {
            double fr = (k < 112) ? (double)k : (double)(k - 224);
            double w = 2.0 * PI_D * fr / 224.0;
            acc += exp(-s2 * w * w) * cos(2.0 * PI_D * (double)k * (double)m / 224.0);
        }
        g_taps[16 + m] = (float)(acc / 224.0);
    }
    g_taps_init = true;
}

// ---------------- launch ----------------
extern "C" void kernel_launch(void* const* d_in, const int* in_sizes, int n_in,
                              void* d_out, int out_size, void* d_ws, size_t ws_size,
                              hipStream_t stream)
{
    const float* x  = (const float*)d_in[0];
    const float* Wl = (const float*)d_in[1];
    const float* bl = (const float*)d_in[2];
    float* out = (float*)d_out;
    float* ws = (float*)d_ws;

    float2* FT224F = (float2*)(ws + OFF_FT224F);
    float2* FT224I = (float2*)(ws + OFF_FT224I);
    float2* FT112I = (float2*)(ws + OFF_FT112I);
    float* TAPS = ws + OFF_PHW;            // [0..15] g1, [16..31] g0
    float* PSI0 = ws + OFF_PSI;
    float* PSI1 = ws + OFF_PSI + 8 * IMG224;
    unsigned* GK = (unsigned*)(ws + OFF_GK);
    float2* XH  = (float2*)(ws + OFF_XH);
    // R32 pools (216MB total, R16-measured-fit):
    float* A0  = ws + OFF_POOL;            // 19267584 floats (192 x 224^2 f2)
    float* A1  = A0 + 19267584;            // 19267584 floats
    float* A23 = A1 + 19267584;            // 9633792 floats (real u1, 192 planes)

    // tables
    host_taps();
    hipMemcpyAsync(TAPS, g_taps, 32 * sizeof(float), hipMemcpyHostToDevice, stream);
    k_fact<<<4, 256, 0, stream>>>(FT224F, 16, 14, -1.0, 1.0, 1);
    k_fact<<<4, 256, 0, stream>>>(FT224I, 16, 14,  1.0, 1.0 / 224.0, 1);
    k_fact<<<1, 256, 0, stream>>>(FT112I, 16, 7,   1.0, 1.0 / 112.0, 0);
    k_psi<<<(16 * IMG224 + 255) / 256, 256, 0, stream>>>(ws + OFF_PSI);
    k_zero<<<(3888 + 255) / 256, 256, 0, stream>>>(GK, 3888);

    // ---- fft2(x) -> XH (R35: packed-real row pass) ----
    rk<16, 14, 4, 1, 128, 2, -1><<<dim3(48, 56), 128, 0, stream>>>(x, 0, nullptr, 0, FT224F, (float2*)A0, 0, 0, 0);
    ck1<16, 14, 2, 64, -1><<<dim3(96, 14), 64, 0, stream>>>((float2*)A0, FT224F, (float2*)A1);
    ck2<16, 14, 2, 0, 64><<<dim3(96, 16), 64, 0, stream>>>((float2*)A1, FT224F, XH, nullptr);

    // ---- s0 = (x (*) g0)(4i,4j) -> slot img*81+0 (R29: 8 bands/img) ----
    s1conv<8, 256><<<48 * 8, 256, 0, stream>>>(x, TAPS + 16, GK, 0, 0, 0);

    // ---- first order j1=1 (8 orientations): fully fused; slot = img*81 + 9 + l ----
    sc2pipe<1024><<<384, 1024, 0, stream>>>(XH, PSI1, TAPS, FT112I, GK, 9, 1, 3);

    // ---- R32: 2x-batched first order j1=0 (+ fused second order); l1 = 4*c2 + f ----
    for (int c2 = 0; c2 < 2; ++c2) {
        // A: ifft rows of xh*psi0[l1] -> A0 (192 groups; 4-per-img XCD mapping)
        rk<16, 14, 4, 1, 128, 0, 1><<<dim3(192, 56), 128, 0, stream>>>(
            XH, 1, PSI0 + (size_t)(4 * c2) * IMG224, 3, FT224I, (float2*)A0, -2, 0, 0);
        // B: ifft cols + |.| -> A23 (real u1, 192 planes)
        ck1<16, 14, 2, 64, 1><<<dim3(384, 14), 64, 0, stream>>>((float2*)A0, FT224I, (float2*)A1);
        ck2<16, 14, 2, 1, 64><<<dim3(384, 16), 64, 0, stream>>>((float2*)A1, FT224I, nullptr, A23);
        // E: s1 = (u1 (*) g0)(4i,4j) -> slot img*81 + 1 + 4*c2 + f (8 bands/group)
        s1conv<8, 256><<<192 * 8, 256, 0, stream>>>(A23, TAPS + 16, GK, 1 + 4 * c2, 2, 3);
        // C (R35): packed-real fft rows of u1 -> A0 (192 groups)
        rk<16, 14, 4, 1, 128, 2, -1><<<dim3(192, 56), 128, 0, stream>>>(A23, 0, nullptr, 0, FT224F, (float2*)A0, 0, 0, 0);
        // D: fft cols -> V1 (A0)
        ck1<16, 14, 2, 64, -1><<<dim3(384, 14), 64, 0, stream>>>((float2*)A0, FT224F, (float2*)A1);
        ck2<16, 14, 2, 0, 64><<<dim3(384, 16), 64, 0, stream>>>((float2*)A1, FT224F, (float2*)A0, nullptr);
        // F: second order fused: 1536 blocks = 48 img x 32 (f,l2); slot = img*81 + 17+32c2 + 8f + l2
        sc2pipe<1024><<<1536, 1024, 0, stream>>>((float2*)A0, PSI1, TAPS, FT112I, GK, 17 + 32 * c2, 4, 5);
    }

    // head
    k_linear<<<(16000 + 255) / 256, 256, 0, stream>>>(GK, Wl, bl, out);
}